// Round 10
// baseline (400.133 us; speedup 1.0000x reference)
//
#include <hip/hip_runtime.h>
#include <hip/hip_bf16.h>
#include <math.h>

// Problem constants (match reference)
#define HEADS 8
#define HC 256            // HEADS*CHAN = D
#define NEG_SLOPE 0.2f    // leaky(t) = 0.6*t + 0.4*|t|

typedef __attribute__((ext_vector_type(8))) short short8;
typedef __attribute__((ext_vector_type(16))) float floatx16;

__device__ inline ushort bf16_rne(float f) {
    unsigned u = __float_as_uint(f);
    return (ushort)((u + 0x7FFFu + ((u >> 16) & 1u)) >> 16);
}

// ---------------------------------------------------------------------------
// fp32 -> bf16 convert of x with XOR-swizzled layout: 16B block j of row r
// stored at block position j ^ (r&7). XOR only permutes within 8-block
// (128B) groups, so any 64-col K-slice stays self-contained (GEMM relies
// on this for per-slice staging).
__global__ __launch_bounds__(256) void cvt_bf16_sw(
        const float* __restrict__ x, ushort* __restrict__ xb, long long nblk) {
    long long id = (long long)blockIdx.x * blockDim.x + threadIdx.x;
    if (id >= nblk) return;
    long long r = id >> 5;
    int j = (int)(id & 31);
    const float4* p = (const float4*)(x + id * 8);
    float4 a = p[0], b = p[1];
    short8 pk;
    pk[0] = (short)bf16_rne(a.x); pk[1] = (short)bf16_rne(a.y);
    pk[2] = (short)bf16_rne(a.z); pk[3] = (short)bf16_rne(a.w);
    pk[4] = (short)bf16_rne(b.x); pk[5] = (short)bf16_rne(b.y);
    pk[6] = (short)bf16_rne(b.z); pk[7] = (short)bf16_rne(b.w);
    int jx = j ^ ((int)r & 7);
    *(short8*)(xb + r * 256 + jx * 8) = pk;
}

// ---------------------------------------------------------------------------
// Pre-transpose weights into wt[n][k] bf16, same XOR swizzle (row = n).
__global__ __launch_bounds__(256) void build_wt(
        const float* __restrict__ Wl, const float* __restrict__ Wr,
        ushort* __restrict__ wt) {
    int n = blockIdx.x;            // 0..511
    int k = threadIdx.x;           // 0..255
    const float* W = (n < 256) ? Wl : Wr;
    int col = n & 255;
    int jx = (k >> 3) ^ (n & 7);
    wt[n * HC + jx * 8 + (k & 7)] = bf16_rne(W[k * HC + col]);
}

// ---------------------------------------------------------------------------
// MFMA dual-GEMM: C[N,512] = A[N,256](bf16,swz) x wt(bf16,swz), bf16 out.
// R14 HYBRID: A staged via global_load_lds DMA (R7's verified path — A is
// 25.6MB, L2-missing; R8 showed scattered A loads die), B fragments read
// DIRECTLY from global (R8's verified index math — wt is 256KB, fully
// L2-resident across the supergroup; no barrier gates these loads -> ILP).
// Halves DMA volume + per-slice drain, halves LDS to 16KB (cap lifted).
// 128x128 C-tile, K sliced 4x64. Supergroup of 32 (8 mt x 4 nt): nt-copies
// of an mt share bid low-3 bits (same XCD) -> A slice L2-hits after first
// touch. 4 waves, each a 64x64 quadrant = 2x2 mfma_32x32x16_bf16 tiles.
__global__ __launch_bounds__(256) void gemm_mfma(
        const ushort* __restrict__ A, const ushort* __restrict__ wt,
        ushort* __restrict__ xl, ushort* __restrict__ xr, int N) {
    __shared__ ushort lA[128 * 64];     // 16 KB
    int mtT = (N + 127) >> 7;           // 391
    int local = blockIdx.x & 31;
    int grp   = blockIdx.x >> 5;
    int mt = grp * 8 + (local & 7);
    int nt = local >> 3;                // 0..3 (128-col slices of 512)
    if (mt >= mtT) return;              // uniform per block, before barriers
    int m0 = mt * 128, n0 = nt * 128;
    int t = threadIdx.x;
    int lane = t & 63, wv = t >> 6;

    // per-lane global byte offset within an 8-row x 128B chunk (A staging)
    int gOff = (lane >> 3) * 512 + (lane & 7) * 16;
    const char* gA = (const char*)A + (long long)m0 * 512;

#define STAGE(KS)                                                              \
    {                                                                          \
        _Pragma("unroll")                                                      \
        for (int i_ = 0; i_ < 4; ++i_) {                                       \
            int rr = wv * 32 + i_ * 8;                                         \
            __builtin_amdgcn_global_load_lds(                                  \
                (const __attribute__((address_space(1))) unsigned int*)        \
                    (gA + (long long)rr * 512 + (KS) * 128 + gOff),            \
                (__attribute__((address_space(3))) unsigned int*)              \
                    (&lA[rr * 64]), 16, 0, 0);                                 \
        }                                                                      \
    }

    int rA0 = (wv & 1) * 64 + (lane & 31);
    int rB0 = (wv >> 1) * 64 + (lane & 31);
    int kh = lane >> 5;                 // k-half of the fragment
    int sA = rA0 & 7, sB = rB0 & 7;     // (r+32)&7 is identical

    // direct-global B row base pointers (verified in R8)
    const char* pB0 = (const char*)wt + (long long)(n0 + rB0) * 512;
    const char* pB1 = pB0 + 32 * 512;

    floatx16 ac00, ac01, ac10, ac11;
    #pragma unroll
    for (int i = 0; i < 16; ++i) { ac00[i] = 0.f; ac01[i] = 0.f;
                                   ac10[i] = 0.f; ac11[i] = 0.f; }

    #pragma unroll
    for (int ks = 0; ks < 4; ++ks) {
        STAGE(ks)
        __syncthreads();                // drains vmcnt(0): lA ready
        #pragma unroll
        for (int kk = 0; kk < 4; ++kk) {
            int jb = kk * 2 + kh;       // 16B k-block within the slice
            int ofB = ks * 128 + ((jb ^ sB) * 16);
            short8 a0 = *(const short8*)&lA[rA0 * 64 + ((jb ^ sA) * 8)];
            short8 a1 = *(const short8*)&lA[(rA0 + 32) * 64 + ((jb ^ sA) * 8)];
            short8 b0 = *(const short8*)(pB0 + ofB);
            short8 b1 = *(const short8*)(pB1 + ofB);
            ac00 = __builtin_amdgcn_mfma_f32_32x32x16_bf16(a0, b0, ac00, 0, 0, 0);
            ac01 = __builtin_amdgcn_mfma_f32_32x32x16_bf16(a0, b1, ac01, 0, 0, 0);
            ac10 = __builtin_amdgcn_mfma_f32_32x32x16_bf16(a1, b0, ac10, 0, 0, 0);
            ac11 = __builtin_amdgcn_mfma_f32_32x32x16_bf16(a1, b1, ac11, 0, 0, 0);
        }
        __syncthreads();                // all lA reads done before next STAGE
    }
#undef STAGE

    // ---- epilogue: C/D layout col=lane&31, row=(reg&3)+8*(reg>>2)+4*kh ----
    ushort* obase = (nt < 2) ? xl : xr;               // xl/xr PLAIN layout
    int colb = (nt & 1) * 128 + (wv >> 1) * 64 + (lane & 31);
    int rbase = m0 + (wv & 1) * 64 + 4 * kh;
    #pragma unroll
    for (int g = 0; g < 4; ++g) {
        #pragma unroll
        for (int q = 0; q < 4; ++q) {
            int row0 = rbase + q + 8 * g;
            int row1 = row0 + 32;
            int e = g * 4 + q;
            if (row0 < N) {
                obase[(long long)row0 * HC + colb]      = bf16_rne(ac00[e]);
                obase[(long long)row0 * HC + colb + 32] = bf16_rne(ac01[e]);
            }
            if (row1 < N) {
                obase[(long long)row1 * HC + colb]      = bf16_rne(ac10[e]);
                obase[(long long)row1 * HC + colb + 32] = bf16_rne(ac11[e]);
            }
        }
    }
}

// ---------------------------------------------------------------------------
// Histogram of dst (self-loops appended implicitly: edge w>=E is node w-E)
__global__ void hist_dst(const int* __restrict__ eidx, int E, int N,
                         int* __restrict__ counts) {
    int w = blockIdx.x * blockDim.x + threadIdx.x;
    int Etot = E + N;
    if (w >= Etot) return;
    int d = (w < E) ? eidx[E + w] : (w - E);
    atomicAdd(&counts[d], 1);
}

// ---------------------------------------------------------------------------
// 3-kernel exclusive scan: per-block scan -> block-sum scan -> add offsets
__global__ __launch_bounds__(1024) void scan_local(
        const int* __restrict__ counts, int* __restrict__ rowptr,
        int* __restrict__ bsum, int N) {
    __shared__ int wsums[16];
    int t = threadIdx.x, lane = t & 63, wv = t >> 6;
    int i = blockIdx.x * 1024 + t;
    int v = (i < N) ? counts[i] : 0;
    int orig = v;
    #pragma unroll
    for (int off = 1; off < 64; off <<= 1) {
        int n = __shfl_up(v, off, 64);
        if (lane >= off) v += n;
    }
    if (lane == 63) wsums[wv] = v;
    __syncthreads();
    int woff = 0, total = 0;
    #pragma unroll
    for (int w_ = 0; w_ < 16; ++w_) {
        int s = wsums[w_];
        if (w_ < wv) woff += s;
        total += s;
    }
    if (i < N) rowptr[i] = v + woff - orig;
    if (t == 0) bsum[blockIdx.x] = total;
}

__global__ void scan_bsums(const int* __restrict__ bsum, int* __restrict__ bsum2,
                           int* __restrict__ rowptr, int nb, int N) {
    int lane = threadIdx.x;   // 64 threads, nb <= 64
    int v = (lane < nb) ? bsum[lane] : 0;
    int orig = v;
    #pragma unroll
    for (int off = 1; off < 64; off <<= 1) {
        int n = __shfl_up(v, off, 64);
        if (lane >= off) v += n;
    }
    if (lane < nb) bsum2[lane] = v - orig;
    if (lane == 63) rowptr[N] = v;
}

__global__ __launch_bounds__(1024) void scan_add(
        int* __restrict__ rowptr, const int* __restrict__ bsum2, int N) {
    int i = blockIdx.x * 1024 + threadIdx.x;
    if (i < N) rowptr[i] += bsum2[blockIdx.x];
}

// ---------------------------------------------------------------------------
// Scatter: store PRE-SCALED byte offsets (s * 512 = s<<9) so gat_node's
// gather address is a single v_or with the lane's channel-byte offset.
__global__ void scatter_edges(const int* __restrict__ eidx, int E, int N,
                              const int* __restrict__ rowptr,
                              int* __restrict__ fill, int* __restrict__ srcS) {
    int w = blockIdx.x * blockDim.x + threadIdx.x;
    int Etot = E + N;
    if (w >= Etot) return;
    int s, d;
    if (w < E) { s = eidx[w]; d = eidx[E + w]; }
    else       { s = w - E;   d = w - E; }
    int pos = rowptr[d] + atomicAdd(&fill[d], 1);
    srcS[pos] = s << 9;          // byte offset of row s (HC * 2B = 512)
}

// ---------------------------------------------------------------------------
// Fused GATv2 per-node: one wave per dst node, ONE-SHOT blocks (4 nodes per
// 256-block). R7 SCALAR version — FROZEN FINAL. Evidence: R2/R3/R4
// restructures regressed; R9's isolated packed-math test showed identical
// wall (74.0 vs 74.5) with LOWER occupancy -> kernel is latency/L3-BW-bound
// (FETCH 200MB @ ~3.45TB/s = ~58us of a 74us wall); instruction-count cuts
// don't pay. Two edges per wave per step (half-waves h=0/1), 8 ch/lane.
// LAYER1: ELU + bf16 SWIZZLED store (feeds layer-2 GEMM DMA); else fp32.
template <int LAYER1>
__global__ __launch_bounds__(256) void gat_node(
        const ushort* __restrict__ xl, const ushort* __restrict__ xr,
        const float* __restrict__ att, const float* __restrict__ bias,
        const int* __restrict__ rowptr, const unsigned* __restrict__ srcB,
        void* __restrict__ outp, int N) {
    int node = blockIdx.x * 4 + (threadIdx.x >> 6);
    int lane = threadIdx.x & 63;
    if (node >= N) return;
    int h = lane >> 5;                       // which edge of the pair
    int q = lane & 31;                       // 16B-block index within row
    unsigned cb = (unsigned)q * 16u;         // byte offset within row
    const char* xbase = (const char*)xl;
    int beg = rowptr[node], end = rowptr[node + 1];

    long long nbase = (long long)node * HC;
    uint4 xu = *(const uint4*)(xr + nbase + q * 8);
    float xr0 = __uint_as_float(xu.x << 16);
    float xr1 = __uint_as_float(xu.x & 0xffff0000u);
    float xr2 = __uint_as_float(xu.y << 16);
    float xr3 = __uint_as_float(xu.y & 0xffff0000u);
    float xr4 = __uint_as_float(xu.z << 16);
    float xr5 = __uint_as_float(xu.z & 0xffff0000u);
    float xr6 = __uint_as_float(xu.w << 16);
    float xr7 = __uint_as_float(xu.w & 0xffff0000u);
    float4 av0 = *(const float4*)(att + q * 8);
    float4 av1 = *(const float4*)(att + q * 8 + 4);

    float ssA = 0.f, ssB = 0.f;
    float aA0 = 0.f, aA1 = 0.f, aA2 = 0.f, aA3 = 0.f;
    float aA4 = 0.f, aA5 = 0.f, aA6 = 0.f, aA7 = 0.f;
    float aB0 = 0.f, aB1 = 0.f, aB2 = 0.f, aB3 = 0.f;
    float aB4 = 0.f, aB5 = 0.f, aB6 = 0.f, aB7 = 0.f;

// EDGE2 processes edges (P, P+h): 2 edges per wave. ALLV=0 -> single valid
// edge at P; half-1 lanes clamp to P and contribute ex=0.
#define EDGE2(P, SFX, ALLV)                                                    \
    {                                                                          \
        int pe = (P) + ((ALLV) ? h : 0);                                       \
        unsigned off = srcB[pe] | cb;                                          \
        uint4 dv = *(const uint4*)(xbase + off);                               \
        float v0 = __uint_as_float(dv.x << 16);                                \
        float v1 = __uint_as_float(dv.x & 0xffff0000u);                        \
        float v2 = __uint_as_float(dv.y << 16);                                \
        float v3 = __uint_as_float(dv.y & 0xffff0000u);                        \
        float v4 = __uint_as_float(dv.z << 16);                                \
        float v5 = __uint_as_float(dv.z & 0xffff0000u);                        \
        float v6 = __uint_as_float(dv.w << 16);                                \
        float v7 = __uint_as_float(dv.w & 0xffff0000u);                        \
        float t0 = v0 + xr0, t1 = v1 + xr1, t2 = v2 + xr2, t3 = v3 + xr3;      \
        float t4 = v4 + xr4, t5 = v5 + xr5, t6 = v6 + xr6, t7 = v7 + xr7;      \
        float st = av0.x * t0;                                                 \
        st = fmaf(av0.y, t1, st); st = fmaf(av0.z, t2, st);                    \
        st = fmaf(av0.w, t3, st); st = fmaf(av1.x, t4, st);                    \
        st = fmaf(av1.y, t5, st); st = fmaf(av1.z, t6, st);                    \
        st = fmaf(av1.w, t7, st);                                              \
        float sa = av0.x * fabsf(t0);                                          \
        sa = fmaf(av0.y, fabsf(t1), sa); sa = fmaf(av0.z, fabsf(t2), sa);      \
        sa = fmaf(av0.w, fabsf(t3), sa); sa = fmaf(av1.x, fabsf(t4), sa);      \
        sa = fmaf(av1.y, fabsf(t5), sa); sa = fmaf(av1.z, fabsf(t6), sa);      \
        sa = fmaf(av1.w, fabsf(t7), sa);                                       \
        float sc = fmaf(0.6f, st, 0.4f * sa);                                  \
        sc += __shfl_xor(sc, 1, 64);                                           \
        sc += __shfl_xor(sc, 2, 64);                                           \
        float ex = ((ALLV) || h == 0) ? __expf(sc) : 0.f;                      \
        ss##SFX += ex;                                                         \
        a##SFX##0 = fmaf(ex, v0, a##SFX##0);                                   \
        a##SFX##1 = fmaf(ex, v1, a##SFX##1);                                   \
        a##SFX##2 = fmaf(ex, v2, a##SFX##2);                                   \
        a##SFX##3 = fmaf(ex, v3, a##SFX##3);                                   \
        a##SFX##4 = fmaf(ex, v4, a##SFX##4);                                   \
        a##SFX##5 = fmaf(ex, v5, a##SFX##5);                                   \
        a##SFX##6 = fmaf(ex, v6, a##SFX##6);                                   \
        a##SFX##7 = fmaf(ex, v7, a##SFX##7);                                   \
    }

    int p = beg;
    for (; p + 4 <= end; p += 4) {           // unroll-2: 4 edges in flight
        EDGE2(p, A, 1)
        EDGE2(p + 2, B, 1)
    }
    if (p + 2 <= end) { EDGE2(p, A, 1) p += 2; }
    if (p < end) { EDGE2(p, B, 0) }
#undef EDGE2

    // merge the two half-wave partial sums (once per node)
    float ss = ssA + ssB;
    ss += __shfl_xor(ss, 32, 64);
    float a0 = aA0 + aB0; a0 += __shfl_xor(a0, 32, 64);
    float a1 = aA1 + aB1; a1 += __shfl_xor(a1, 32, 64);
    float a2 = aA2 + aB2; a2 += __shfl_xor(a2, 32, 64);
    float a3 = aA3 + aB3; a3 += __shfl_xor(a3, 32, 64);
    float a4 = aA4 + aB4; a4 += __shfl_xor(a4, 32, 64);
    float a5 = aA5 + aB5; a5 += __shfl_xor(a5, 32, 64);
    float a6 = aA6 + aB6; a6 += __shfl_xor(a6, 32, 64);
    float a7 = aA7 + aB7; a7 += __shfl_xor(a7, 32, 64);

    float inv = 1.f / ss;
    float4 bv0 = *(const float4*)(bias + q * 8);
    float4 bv1 = *(const float4*)(bias + q * 8 + 4);
    float o0 = fmaf(a0, inv, bv0.x);
    float o1 = fmaf(a1, inv, bv0.y);
    float o2 = fmaf(a2, inv, bv0.z);
    float o3 = fmaf(a3, inv, bv0.w);
    float o4 = fmaf(a4, inv, bv1.x);
    float o5 = fmaf(a5, inv, bv1.y);
    float o6 = fmaf(a6, inv, bv1.z);
    float o7 = fmaf(a7, inv, bv1.w);

    if (LAYER1) {
        // each half stores its 4 channels of the 16B block q
        float s0 = h ? o4 : o0;
        float s1 = h ? o5 : o1;
        float s2 = h ? o6 : o2;
        float s3 = h ? o7 : o3;
        s0 = s0 > 0.f ? s0 : expm1f(s0);
        s1 = s1 > 0.f ? s1 : expm1f(s1);
        s2 = s2 > 0.f ? s2 : expm1f(s2);
        s3 = s3 > 0.f ? s3 : expm1f(s3);
        ushort4 pk;
        pk.x = bf16_rne(s0); pk.y = bf16_rne(s1);
        pk.z = bf16_rne(s2); pk.w = bf16_rne(s3);
        int jx = q ^ (node & 7);             // swizzled 16B-block position
        *(ushort4*)((ushort*)outp + nbase + jx * 8 + h * 4) = pk;
    } else {
        float4 ov = h ? make_float4(o4, o5, o6, o7)
                      : make_float4(o0, o1, o2, o3);
        *(float4*)((float*)outp + nbase + q * 8 + h * 4) = ov;
    }
}

// ---------------------------------------------------------------------------
extern "C" void kernel_launch(void* const* d_in, const int* in_sizes, int n_in,
                              void* d_out, int out_size, void* d_ws, size_t ws_size,
                              hipStream_t stream) {
    const float* x    = (const float*)d_in[0];
    const int*   eidx = (const int*)d_in[1];
    const float* Wl1  = (const float*)d_in[2];
    const float* Wr1  = (const float*)d_in[3];
    const float* att1 = (const float*)d_in[4];
    const float* b1   = (const float*)d_in[5];
    const float* Wl2  = (const float*)d_in[6];
    const float* Wr2  = (const float*)d_in[7];
    const float* att2 = (const float*)d_in[8];
    const float* b2   = (const float*)d_in[9];
    float* out = (float*)d_out;

    const int N = in_sizes[0] / HC;       // 50000
    const int E = in_sizes[1] / 2;        // 800000
    const int Etot = E + N;
    const long long NHC = (long long)N * HC;

    // workspace layout (16B-aligned bf16 region first)
    ushort* xl   = (ushort*)d_ws;         // N*HC bf16 (plain)
    ushort* xr   = xl + NHC;              // N*HC     (plain)
    ushort* hbuf = xr + NHC;              // N*HC     (swizzled)
    ushort* xb   = hbuf + NHC;            // N*HC     (swizzled)
    ushort* wt1  = xb + NHC;              // 512*HC   (swizzled)
    ushort* wt2  = wt1 + 512 * HC;        // 512*HC   (swizzled)
    int* rowptr  = (int*)(wt2 + 512 * HC);// N+1
    int* counts  = rowptr + (N + 1);      // N
    int* fill    = counts + N;            // N (contiguous with counts)
    int* bsum    = fill + N;              // 64
    int* bsum2   = bsum + 64;             // 64
    int* srcS    = bsum2 + 64;            // Etot

    const int TB = 256;
    dim3 blk(TB);
    int gEdgesT = (Etot + TB - 1) / TB;
    int mtTiles = (N + 127) / 128;                // 391
    int gGemm   = ((mtTiles + 7) / 8) * 32;       // supergrouped (8 mt x 4 nt)
    int gNode   = (N + 3) / 4;
    int nb      = (N + 1023) / 1024;      // 49 <= 64
    long long nblk = NHC / 8;
    int gCvt    = (int)((nblk + TB - 1) / TB);

    // ---- one-time conversions + CSR build (R5/R7-proven sequence) ----
    cvt_bf16_sw<<<gCvt, blk, 0, stream>>>(x, xb, nblk);
    build_wt<<<512, blk, 0, stream>>>(Wl1, Wr1, wt1);
    build_wt<<<512, blk, 0, stream>>>(Wl2, Wr2, wt2);
    hipMemsetAsync(counts, 0, (size_t)2 * N * sizeof(int), stream);
    hist_dst<<<gEdgesT, blk, 0, stream>>>(eidx, E, N, counts);
    scan_local<<<nb, 1024, 0, stream>>>(counts, rowptr, bsum, N);
    scan_bsums<<<1, 64, 0, stream>>>(bsum, bsum2, rowptr, nb, N);
    scan_add<<<nb, 1024, 0, stream>>>(rowptr, bsum2, N);
    scatter_edges<<<gEdgesT, blk, 0, stream>>>(eidx, E, N, rowptr, fill, srcS);

    // ================= layer 1 =================
    gemm_mfma<<<gGemm, blk, 0, stream>>>(xb, wt1, xl, xr, N);
    gat_node<1><<<gNode, blk, 0, stream>>>(xl, xr, att1, b1, rowptr,
                                           (const unsigned*)srcS, hbuf, N);

    // ================= layer 2 =================
    gemm_mfma<<<gGemm, blk, 0, stream>>>(hbuf, wt2, xl, xr, N);
    gat_node<0><<<gNode, blk, 0, stream>>>(xl, xr, att2, b2, rowptr,
                                           (const unsigned*)srcS, out, N);
}

// Round 11
// 392.478 us; speedup vs baseline: 1.0195x; 1.0195x over previous
//
#include <hip/hip_runtime.h>
#include <hip/hip_bf16.h>
#include <math.h>

// Problem constants (match reference)
#define HEADS 8
#define HC 256            // HEADS*CHAN = D
#define NEG_SLOPE 0.2f    // leaky(t) = 0.6*t + 0.4*|t|

typedef __attribute__((ext_vector_type(8))) short short8;
typedef __attribute__((ext_vector_type(16))) float floatx16;

__device__ inline ushort bf16_rne(float f) {
    unsigned u = __float_as_uint(f);
    return (ushort)((u + 0x7FFFu + ((u >> 16) & 1u)) >> 16);
}

// ---------------------------------------------------------------------------
// fp32 -> bf16 convert of x with XOR-swizzled layout: 16B block j of row r
// stored at block position j ^ (r&7). XOR only permutes within 8-block
// (128B) groups, so any 64-col K-slice stays self-contained (GEMM relies
// on this for per-slice staging).
__global__ __launch_bounds__(256) void cvt_bf16_sw(
        const float* __restrict__ x, ushort* __restrict__ xb, long long nblk) {
    long long id = (long long)blockIdx.x * blockDim.x + threadIdx.x;
    if (id >= nblk) return;
    long long r = id >> 5;
    int j = (int)(id & 31);
    const float4* p = (const float4*)(x + id * 8);
    float4 a = p[0], b = p[1];
    short8 pk;
    pk[0] = (short)bf16_rne(a.x); pk[1] = (short)bf16_rne(a.y);
    pk[2] = (short)bf16_rne(a.z); pk[3] = (short)bf16_rne(a.w);
    pk[4] = (short)bf16_rne(b.x); pk[5] = (short)bf16_rne(b.y);
    pk[6] = (short)bf16_rne(b.z); pk[7] = (short)bf16_rne(b.w);
    int jx = j ^ ((int)r & 7);
    *(short8*)(xb + r * 256 + jx * 8) = pk;
}

// ---------------------------------------------------------------------------
// Pre-transpose BOTH layers' weights into wt[n][k] bf16, same XOR swizzle
// (row = n). One 1024-block launch: blocks [0,512) -> wt1, [512,1024) -> wt2
// (wave-uniform select; per-thread indexing identical to the proven R7
// build_wt). Saves one dispatch.
__global__ __launch_bounds__(256) void build_wt2(
        const float* __restrict__ Wl1, const float* __restrict__ Wr1,
        ushort* __restrict__ wt1,
        const float* __restrict__ Wl2, const float* __restrict__ Wr2,
        ushort* __restrict__ wt2) {
    int b = blockIdx.x;            // 0..1023
    const float* Wl = (b < 512) ? Wl1 : Wl2;
    const float* Wr = (b < 512) ? Wr1 : Wr2;
    ushort* wt = (b < 512) ? wt1 : wt2;
    int n = b & 511;
    int k = threadIdx.x;           // 0..255
    const float* W = (n < 256) ? Wl : Wr;
    int col = n & 255;
    int jx = (k >> 3) ^ (n & 7);
    wt[n * HC + jx * 8 + (k & 7)] = bf16_rne(W[k * HC + col]);
}

// ---------------------------------------------------------------------------
// MFMA dual-GEMM: C[N,512] = A[N,256](bf16,swz) x wt(bf16,swz), bf16 out.
// R7-PROVEN version (390.4 us total) — FROZEN FINAL. 128x128 C-tile, K
// sliced 4x64, SINGLE-buffered 32KB LDS -> 5 blocks/CU. Variant ledger:
// dbuf-64KB (R5, 2blk/CU) < sbuf-32KB (R7, THIS) > hybrid B-direct (R10,
// -10us: unhidden L2-latency chains on B) > zero-LDS (R8, -46us: scattered
// 512B-stride fragment loads). Do not restructure again.
// Supergroup of 32 (8 mt x 4 nt): nt-copies of an mt share bid low-3 bits
// (same XCD under round-robin) -> A slice L2-hits after first touch.
// 4 waves, each a 64x64 quadrant = 2x2 mfma_32x32x16_bf16 tiles.
__global__ __launch_bounds__(256) void gemm_mfma(
        const ushort* __restrict__ A, const ushort* __restrict__ wt,
        ushort* __restrict__ xl, ushort* __restrict__ xr, int N) {
    __shared__ ushort lA[128 * 64];
    __shared__ ushort lB[128 * 64];
    int mtT = (N + 127) >> 7;           // 391
    int local = blockIdx.x & 31;
    int grp   = blockIdx.x >> 5;
    int mt = grp * 8 + (local & 7);
    int nt = local >> 3;                // 0..3 (128-col slices of 512)
    if (mt >= mtT) return;              // uniform per block, before barriers
    int m0 = mt * 128, n0 = nt * 128;
    int t = threadIdx.x;
    int lane = t & 63, wv = t >> 6;

    // per-lane global byte offset within an 8-row x 128B chunk
    int gOff = (lane >> 3) * 512 + (lane & 7) * 16;
    const char* gA = (const char*)A + (long long)m0 * 512;
    const char* gB = (const char*)wt + (long long)n0 * 512;

#define STAGE(KS)                                                              \
    {                                                                          \
        _Pragma("unroll")                                                      \
        for (int i_ = 0; i_ < 4; ++i_) {                                       \
            int rr = wv * 32 + i_ * 8;                                         \
            __builtin_amdgcn_global_load_lds(                                  \
                (const __attribute__((address_space(1))) unsigned int*)        \
                    (gA + (long long)rr * 512 + (KS) * 128 + gOff),            \
                (__attribute__((address_space(3))) unsigned int*)              \
                    (&lA[rr * 64]), 16, 0, 0);                                 \
            __builtin_amdgcn_global_load_lds(                                  \
                (const __attribute__((address_space(1))) unsigned int*)        \
                    (gB + (long long)rr * 512 + (KS) * 128 + gOff),            \
                (__attribute__((address_space(3))) unsigned int*)              \
                    (&lB[rr * 64]), 16, 0, 0);                                 \
        }                                                                      \
    }

    int rA0 = (wv & 1) * 64 + (lane & 31);
    int rB0 = (wv >> 1) * 64 + (lane & 31);
    int kh = lane >> 5;                 // k-half of the fragment
    int sA = rA0 & 7, sB = rB0 & 7;     // (r+32)&7 is identical
    floatx16 ac00, ac01, ac10, ac11;
    #pragma unroll
    for (int i = 0; i < 16; ++i) { ac00[i] = 0.f; ac01[i] = 0.f;
                                   ac10[i] = 0.f; ac11[i] = 0.f; }

    #pragma unroll
    for (int ks = 0; ks < 4; ++ks) {
        STAGE(ks)
        __syncthreads();                // drains vmcnt(0): LDS ready
        #pragma unroll
        for (int kk = 0; kk < 4; ++kk) {
            int jb = kk * 2 + kh;       // 16B k-block within the slice
            short8 a0 = *(const short8*)&lA[rA0 * 64 + ((jb ^ sA) * 8)];
            short8 a1 = *(const short8*)&lA[(rA0 + 32) * 64 + ((jb ^ sA) * 8)];
            short8 b0 = *(const short8*)&lB[rB0 * 64 + ((jb ^ sB) * 8)];
            short8 b1 = *(const short8*)&lB[(rB0 + 32) * 64 + ((jb ^ sB) * 8)];
            ac00 = __builtin_amdgcn_mfma_f32_32x32x16_bf16(a0, b0, ac00, 0, 0, 0);
            ac01 = __builtin_amdgcn_mfma_f32_32x32x16_bf16(a0, b1, ac01, 0, 0, 0);
            ac10 = __builtin_amdgcn_mfma_f32_32x32x16_bf16(a1, b0, ac10, 0, 0, 0);
            ac11 = __builtin_amdgcn_mfma_f32_32x32x16_bf16(a1, b1, ac11, 0, 0, 0);
        }
        __syncthreads();                // all ds_reads done before next STAGE
    }
#undef STAGE

    // ---- epilogue: C/D layout col=lane&31, row=(reg&3)+8*(reg>>2)+4*kh ----
    ushort* obase = (nt < 2) ? xl : xr;               // xl/xr PLAIN layout
    int colb = (nt & 1) * 128 + (wv >> 1) * 64 + (lane & 31);
    int rbase = m0 + (wv & 1) * 64 + 4 * kh;
    #pragma unroll
    for (int g = 0; g < 4; ++g) {
        #pragma unroll
        for (int q = 0; q < 4; ++q) {
            int row0 = rbase + q + 8 * g;
            int row1 = row0 + 32;
            int e = g * 4 + q;
            if (row0 < N) {
                obase[(long long)row0 * HC + colb]      = bf16_rne(ac00[e]);
                obase[(long long)row0 * HC + colb + 32] = bf16_rne(ac01[e]);
            }
            if (row1 < N) {
                obase[(long long)row1 * HC + colb]      = bf16_rne(ac10[e]);
                obase[(long long)row1 * HC + colb + 32] = bf16_rne(ac11[e]);
            }
        }
    }
}

// ---------------------------------------------------------------------------
// Histogram of dst (self-loops appended implicitly: edge w>=E is node w-E)
__global__ void hist_dst(const int* __restrict__ eidx, int E, int N,
                         int* __restrict__ counts) {
    int w = blockIdx.x * blockDim.x + threadIdx.x;
    int Etot = E + N;
    if (w >= Etot) return;
    int d = (w < E) ? eidx[E + w] : (w - E);
    atomicAdd(&counts[d], 1);
}

// ---------------------------------------------------------------------------
// 3-kernel exclusive scan: per-block scan -> block-sum scan -> add offsets
__global__ __launch_bounds__(1024) void scan_local(
        const int* __restrict__ counts, int* __restrict__ rowptr,
        int* __restrict__ bsum, int N) {
    __shared__ int wsums[16];
    int t = threadIdx.x, lane = t & 63, wv = t >> 6;
    int i = blockIdx.x * 1024 + t;
    int v = (i < N) ? counts[i] : 0;
    int orig = v;
    #pragma unroll
    for (int off = 1; off < 64; off <<= 1) {
        int n = __shfl_up(v, off, 64);
        if (lane >= off) v += n;
    }
    if (lane == 63) wsums[wv] = v;
    __syncthreads();
    int woff = 0, total = 0;
    #pragma unroll
    for (int w_ = 0; w_ < 16; ++w_) {
        int s = wsums[w_];
        if (w_ < wv) woff += s;
        total += s;
    }
    if (i < N) rowptr[i] = v + woff - orig;
    if (t == 0) bsum[blockIdx.x] = total;
}

__global__ void scan_bsums(const int* __restrict__ bsum, int* __restrict__ bsum2,
                           int* __restrict__ rowptr, int nb, int N) {
    int lane = threadIdx.x;   // 64 threads, nb <= 64
    int v = (lane < nb) ? bsum[lane] : 0;
    int orig = v;
    #pragma unroll
    for (int off = 1; off < 64; off <<= 1) {
        int n = __shfl_up(v, off, 64);
        if (lane >= off) v += n;
    }
    if (lane < nb) bsum2[lane] = v - orig;
    if (lane == 63) rowptr[N] = v;
}

__global__ __launch_bounds__(1024) void scan_add(
        int* __restrict__ rowptr, const int* __restrict__ bsum2, int N) {
    int i = blockIdx.x * 1024 + threadIdx.x;
    if (i < N) rowptr[i] += bsum2[blockIdx.x];
}

// ---------------------------------------------------------------------------
// Scatter: store PRE-SCALED byte offsets (s * 512 = s<<9) so gat_node's
// gather address is a single v_or with the lane's channel-byte offset.
__global__ void scatter_edges(const int* __restrict__ eidx, int E, int N,
                              const int* __restrict__ rowptr,
                              int* __restrict__ fill, int* __restrict__ srcS) {
    int w = blockIdx.x * blockDim.x + threadIdx.x;
    int Etot = E + N;
    if (w >= Etot) return;
    int s, d;
    if (w < E) { s = eidx[w]; d = eidx[E + w]; }
    else       { s = w - E;   d = w - E; }
    int pos = rowptr[d] + atomicAdd(&fill[d], 1);
    srcS[pos] = s << 9;          // byte offset of row s (HC * 2B = 512)
}

// ---------------------------------------------------------------------------
// Fused GATv2 per-node: one wave per dst node, ONE-SHOT blocks (4 nodes per
// 256-block). R7 SCALAR version — FROZEN FINAL. Evidence: R2/R3/R4
// restructures regressed; R9's isolated packed-math test showed identical
// wall (74.0 vs 74.5) with LOWER occupancy -> kernel is latency/L3-BW-bound
// (FETCH 200MB @ ~3.45TB/s = ~58us of a 74us wall); instruction-count cuts
// don't pay. Two edges per wave per step (half-waves h=0/1), 8 ch/lane.
// LAYER1: ELU + bf16 SWIZZLED store (feeds layer-2 GEMM DMA); else fp32.
template <int LAYER1>
__global__ __launch_bounds__(256) void gat_node(
        const ushort* __restrict__ xl, const ushort* __restrict__ xr,
        const float* __restrict__ att, const float* __restrict__ bias,
        const int* __restrict__ rowptr, const unsigned* __restrict__ srcB,
        void* __restrict__ outp, int N) {
    int node = blockIdx.x * 4 + (threadIdx.x >> 6);
    int lane = threadIdx.x & 63;
    if (node >= N) return;
    int h = lane >> 5;                       // which edge of the pair
    int q = lane & 31;                       // 16B-block index within row
    unsigned cb = (unsigned)q * 16u;         // byte offset within row
    const char* xbase = (const char*)xl;
    int beg = rowptr[node], end = rowptr[node + 1];

    long long nbase = (long long)node * HC;
    uint4 xu = *(const uint4*)(xr + nbase + q * 8);
    float xr0 = __uint_as_float(xu.x << 16);
    float xr1 = __uint_as_float(xu.x & 0xffff0000u);
    float xr2 = __uint_as_float(xu.y << 16);
    float xr3 = __uint_as_float(xu.y & 0xffff0000u);
    float xr4 = __uint_as_float(xu.z << 16);
    float xr5 = __uint_as_float(xu.z & 0xffff0000u);
    float xr6 = __uint_as_float(xu.w << 16);
    float xr7 = __uint_as_float(xu.w & 0xffff0000u);
    float4 av0 = *(const float4*)(att + q * 8);
    float4 av1 = *(const float4*)(att + q * 8 + 4);

    float ssA = 0.f, ssB = 0.f;
    float aA0 = 0.f, aA1 = 0.f, aA2 = 0.f, aA3 = 0.f;
    float aA4 = 0.f, aA5 = 0.f, aA6 = 0.f, aA7 = 0.f;
    float aB0 = 0.f, aB1 = 0.f, aB2 = 0.f, aB3 = 0.f;
    float aB4 = 0.f, aB5 = 0.f, aB6 = 0.f, aB7 = 0.f;

// EDGE2 processes edges (P, P+h): 2 edges per wave. ALLV=0 -> single valid
// edge at P; half-1 lanes clamp to P and contribute ex=0.
#define EDGE2(P, SFX, ALLV)                                                    \
    {                                                                          \
        int pe = (P) + ((ALLV) ? h : 0);                                       \
        unsigned off = srcB[pe] | cb;                                          \
        uint4 dv = *(const uint4*)(xbase + off);                               \
        float v0 = __uint_as_float(dv.x << 16);                                \
        float v1 = __uint_as_float(dv.x & 0xffff0000u);                        \
        float v2 = __uint_as_float(dv.y << 16);                                \
        float v3 = __uint_as_float(dv.y & 0xffff0000u);                        \
        float v4 = __uint_as_float(dv.z << 16);                                \
        float v5 = __uint_as_float(dv.z & 0xffff0000u);                        \
        float v6 = __uint_as_float(dv.w << 16);                                \
        float v7 = __uint_as_float(dv.w & 0xffff0000u);                        \
        float t0 = v0 + xr0, t1 = v1 + xr1, t2 = v2 + xr2, t3 = v3 + xr3;      \
        float t4 = v4 + xr4, t5 = v5 + xr5, t6 = v6 + xr6, t7 = v7 + xr7;      \
        float st = av0.x * t0;                                                 \
        st = fmaf(av0.y, t1, st); st = fmaf(av0.z, t2, st);                    \
        st = fmaf(av0.w, t3, st); st = fmaf(av1.x, t4, st);                    \
        st = fmaf(av1.y, t5, st); st = fmaf(av1.z, t6, st);                    \
        st = fmaf(av1.w, t7, st);                                              \
        float sa = av0.x * fabsf(t0);                                          \
        sa = fmaf(av0.y, fabsf(t1), sa); sa = fmaf(av0.z, fabsf(t2), sa);      \
        sa = fmaf(av0.w, fabsf(t3), sa); sa = fmaf(av1.x, fabsf(t4), sa);      \
        sa = fmaf(av1.y, fabsf(t5), sa); sa = fmaf(av1.z, fabsf(t6), sa);      \
        sa = fmaf(av1.w, fabsf(t7), sa);                                       \
        float sc = fmaf(0.6f, st, 0.4f * sa);                                  \
        sc += __shfl_xor(sc, 1, 64);                                           \
        sc += __shfl_xor(sc, 2, 64);                                           \
        float ex = ((ALLV) || h == 0) ? __expf(sc) : 0.f;                      \
        ss##SFX += ex;                                                         \
        a##SFX##0 = fmaf(ex, v0, a##SFX##0);                                   \
        a##SFX##1 = fmaf(ex, v1, a##SFX##1);                                   \
        a##SFX##2 = fmaf(ex, v2, a##SFX##2);                                   \
        a##SFX##3 = fmaf(ex, v3, a##SFX##3);                                   \
        a##SFX##4 = fmaf(ex, v4, a##SFX##4);                                   \
        a##SFX##5 = fmaf(ex, v5, a##SFX##5);                                   \
        a##SFX##6 = fmaf(ex, v6, a##SFX##6);                                   \
        a##SFX##7 = fmaf(ex, v7, a##SFX##7);                                   \
    }

    int p = beg;
    for (; p + 4 <= end; p += 4) {           // unroll-2: 4 edges in flight
        EDGE2(p, A, 1)
        EDGE2(p + 2, B, 1)
    }
    if (p + 2 <= end) { EDGE2(p, A, 1) p += 2; }
    if (p < end) { EDGE2(p, B, 0) }
#undef EDGE2

    // merge the two half-wave partial sums (once per node)
    float ss = ssA + ssB;
    ss += __shfl_xor(ss, 32, 64);
    float a0 = aA0 + aB0; a0 += __shfl_xor(a0, 32, 64);
    float a1 = aA1 + aB1; a1 += __shfl_xor(a1, 32, 64);
    float a2 = aA2 + aB2; a2 += __shfl_xor(a2, 32, 64);
    float a3 = aA3 + aB3; a3 += __shfl_xor(a3, 32, 64);
    float a4 = aA4 + aB4; a4 += __shfl_xor(a4, 32, 64);
    float a5 = aA5 + aB5; a5 += __shfl_xor(a5, 32, 64);
    float a6 = aA6 + aB6; a6 += __shfl_xor(a6, 32, 64);
    float a7 = aA7 + aB7; a7 += __shfl_xor(a7, 32, 64);

    float inv = 1.f / ss;
    float4 bv0 = *(const float4*)(bias + q * 8);
    float4 bv1 = *(const float4*)(bias + q * 8 + 4);
    float o0 = fmaf(a0, inv, bv0.x);
    float o1 = fmaf(a1, inv, bv0.y);
    float o2 = fmaf(a2, inv, bv0.z);
    float o3 = fmaf(a3, inv, bv0.w);
    float o4 = fmaf(a4, inv, bv1.x);
    float o5 = fmaf(a5, inv, bv1.y);
    float o6 = fmaf(a6, inv, bv1.z);
    float o7 = fmaf(a7, inv, bv1.w);

    if (LAYER1) {
        // each half stores its 4 channels of the 16B block q
        float s0 = h ? o4 : o0;
        float s1 = h ? o5 : o1;
        float s2 = h ? o6 : o2;
        float s3 = h ? o7 : o3;
        s0 = s0 > 0.f ? s0 : expm1f(s0);
        s1 = s1 > 0.f ? s1 : expm1f(s1);
        s2 = s2 > 0.f ? s2 : expm1f(s2);
        s3 = s3 > 0.f ? s3 : expm1f(s3);
        ushort4 pk;
        pk.x = bf16_rne(s0); pk.y = bf16_rne(s1);
        pk.z = bf16_rne(s2); pk.w = bf16_rne(s3);
        int jx = q ^ (node & 7);             // swizzled 16B-block position
        *(ushort4*)((ushort*)outp + nbase + jx * 8 + h * 4) = pk;
    } else {
        float4 ov = h ? make_float4(o4, o5, o6, o7)
                      : make_float4(o0, o1, o2, o3);
        *(float4*)((float*)outp + nbase + q * 8 + h * 4) = ov;
    }
}

// ---------------------------------------------------------------------------
extern "C" void kernel_launch(void* const* d_in, const int* in_sizes, int n_in,
                              void* d_out, int out_size, void* d_ws, size_t ws_size,
                              hipStream_t stream) {
    const float* x    = (const float*)d_in[0];
    const int*   eidx = (const int*)d_in[1];
    const float* Wl1  = (const float*)d_in[2];
    const float* Wr1  = (const float*)d_in[3];
    const float* att1 = (const float*)d_in[4];
    const float* b1   = (const float*)d_in[5];
    const float* Wl2  = (const float*)d_in[6];
    const float* Wr2  = (const float*)d_in[7];
    const float* att2 = (const float*)d_in[8];
    const float* b2   = (const float*)d_in[9];
    float* out = (float*)d_out;

    const int N = in_sizes[0] / HC;       // 50000
    const int E = in_sizes[1] / 2;        // 800000
    const int Etot = E + N;
    const long long NHC = (long long)N * HC;

    // workspace layout (16B-aligned bf16 region first)
    ushort* xl   = (ushort*)d_ws;         // N*HC bf16 (plain)
    ushort* xr   = xl + NHC;              // N*HC     (plain)
    ushort* hbuf = xr + NHC;              // N*HC     (swizzled)
    ushort* xb   = hbuf + NHC;            // N*HC     (swizzled)
    ushort* wt1  = xb + NHC;              // 512*HC   (swizzled)
    ushort* wt2  = wt1 + 512 * HC;        // 512*HC   (swizzled)
    int* rowptr  = (int*)(wt2 + 512 * HC);// N+1
    int* counts  = rowptr + (N + 1);      // N
    int* fill    = counts + N;            // N (contiguous with counts)
    int* bsum    = fill + N;              // 64
    int* bsum2   = bsum + 64;             // 64
    int* srcS    = bsum2 + 64;            // Etot

    const int TB = 256;
    dim3 blk(TB);
    int gEdgesT = (Etot + TB - 1) / TB;
    int mtTiles = (N + 127) / 128;                // 391
    int gGemm   = ((mtTiles + 7) / 8) * 32;       // supergrouped (8 mt x 4 nt)
    int gNode   = (N + 3) / 4;
    int nb      = (N + 1023) / 1024;      // 49 <= 64
    long long nblk = NHC / 8;
    int gCvt    = (int)((nblk + TB - 1) / TB);

    // ---- one-time conversions + CSR build (R7-proven sequence; both
    //      weight transposes in one launch) ----
    cvt_bf16_sw<<<gCvt, blk, 0, stream>>>(x, xb, nblk);
    build_wt2<<<1024, blk, 0, stream>>>(Wl1, Wr1, wt1, Wl2, Wr2, wt2);
    hipMemsetAsync(counts, 0, (size_t)2 * N * sizeof(int), stream);
    hist_dst<<<gEdgesT, blk, 0, stream>>>(eidx, E, N, counts);
    scan_local<<<nb, 1024, 0, stream>>>(counts, rowptr, bsum, N);
    scan_bsums<<<1, 64, 0, stream>>>(bsum, bsum2, rowptr, nb, N);
    scan_add<<<nb, 1024, 0, stream>>>(rowptr, bsum2, N);
    scatter_edges<<<gEdgesT, blk, 0, stream>>>(eidx, E, N, rowptr, fill, srcS);

    // ================= layer 1 =================
    gemm_mfma<<<gGemm, blk, 0, stream>>>(xb, wt1, xl, xr, N);
    gat_node<1><<<gNode, blk, 0, stream>>>(xl, xr, att1, b1, rowptr,
                                           (const unsigned*)srcS, hbuf, N);

    // ================= layer 2 =================
    gemm_mfma<<<gGemm, blk, 0, stream>>>(hbuf, wt2, xl, xr, N);
    gat_node<0><<<gNode, blk, 0, stream>>>(xl, xr, att2, b2, rowptr,
                                           (const unsigned*)srcS, out, N);
}